// Round 7
// baseline (233.103 us; speedup 1.0000x reference)
//
#include <hip/hip_runtime.h>
#include <hip/hip_bf16.h>

typedef __attribute__((ext_vector_type(8))) short short8;
typedef __attribute__((ext_vector_type(4))) float f32x4;
typedef __attribute__((ext_vector_type(4))) unsigned short u16x4;

__device__ __forceinline__ unsigned short f2bf(float f) {
  union { float f; unsigned u; } v; v.f = f;
  unsigned r = v.u + 0x7fffu + ((v.u >> 16) & 1u);
  return (unsigned short)(r >> 16);
}

// C = A * Bt^T. 512 threads = 8 waves (2M x 4N), wave-tile (MI*16) x 64,
// BK=64, 2-phase double-buffered prefetch (proven race-free structure).
// EPI=0: MI=8 -> tile 256x256; epilogue: W bf16 via swizzled LDS bounce +
//        row-sum partials into part[(bn*4+wn)][row] (unique writer).
// EPI=1: MI=4 -> tile 128x256; epilogue: out fp32 scaled by 1/(denin+1e-8),
//        via LDS bounce -> coalesced nontemporal stores.
// LDS staging swizzle: row r (8x16B chunks) holds global chunk c^(r&7) at
// slot c; applied global-side (linear gload_lds dest) + reader-side.
template <int EPI, int MI>
__global__ __launch_bounds__(512, 2) void rbf_gemm(
    const unsigned short* __restrict__ A, const unsigned short* __restrict__ Bt,
    int Ncols, int K,
    const float* __restrict__ xsq, const float* __restrict__ psq,
    const float* __restrict__ rtemp, unsigned short* __restrict__ Wout,
    float* __restrict__ part, int Mtot, const float* __restrict__ denin,
    float* __restrict__ outp, int row0, int ldOut) {
  constexpr int BM = MI * 32;          // 256 or 128
  constexpr int AITERS = BM / 64;      // 4 or 2
  constexpr int ASZ = BM * 64;         // A elems per K-tile
  constexpr int HALF = ASZ + 16384;    // + B (256 rows x 64)
  __shared__ __align__(16) unsigned short smem[65536];  // 128 KB

  const int t = threadIdx.x;
  const int lane = t & 63, wid = t >> 6;
  const int wm = wid >> 2, wn = wid & 3;   // 2M x 4N waves
  const int lr = lane & 15, lg = lane >> 4;

  const int nb = Ncols >> 8;
  const int nwg = gridDim.x;
  int swz = blockIdx.x;
  if ((nwg & 7) == 0) {  // bijective XCD swizzle
    int cpx = nwg >> 3;
    swz = (swz & 7) * cpx + (swz >> 3);
  }
  const int bm = swz / nb, bn = swz - bm * nb;

  const unsigned short* Ab = A + (size_t)bm * BM * K;
  const unsigned short* Bb = Bt + (size_t)bn * 256 * K;

  // staging source pointers (swizzled chunk), advance by koff per step
  const unsigned short* gA[AITERS];
  const unsigned short* gB[4];
#pragma unroll
  for (int i = 0; i < AITERS; ++i) {
    const int idx = i * 512 + t;
    const int r = idx >> 3, c = idx & 7;
    gA[i] = Ab + (size_t)r * K + ((c ^ (r & 7)) << 3);
  }
#pragma unroll
  for (int i = 0; i < 4; ++i) {
    const int idx = i * 512 + t;
    const int r = idx >> 3, c = idx & 7;
    gB[i] = Bb + (size_t)r * K + ((c ^ (r & 7)) << 3);
  }
  const int dwave = wid << 9;  // wave-uniform LDS elem base within a 512-slot group

  // fragment LDS element offsets (reader applies same swizzle)
  int offA[MI][2], offB[4][2];
#pragma unroll
  for (int mi = 0; mi < MI; ++mi) {
    const int ar = wm * (MI * 16) + mi * 16 + lr;
#pragma unroll
    for (int ks = 0; ks < 2; ++ks)
      offA[mi][ks] = ar * 64 + ((((ks << 2) | lg) ^ (ar & 7)) << 3);
  }
#pragma unroll
  for (int ni = 0; ni < 4; ++ni) {
    const int br = wn * 64 + ni * 16 + lr;
#pragma unroll
    for (int ks = 0; ks < 2; ++ks)
      offB[ni][ks] = ASZ + br * 64 + ((((ks << 2) | lg) ^ (br & 7)) << 3);
  }

  f32x4 acc[MI][4];
#pragma unroll
  for (int i = 0; i < MI; ++i)
#pragma unroll
    for (int j = 0; j < 4; ++j) acc[i][j] = (f32x4){0.f, 0.f, 0.f, 0.f};

#define STAGE(koff, boff)                                                              \
  do {                                                                                 \
    _Pragma("unroll")                                                                  \
    for (int i = 0; i < AITERS; ++i)                                                   \
      __builtin_amdgcn_global_load_lds(                                                \
          (const __attribute__((address_space(1))) void*)(gA[i] + (koff)),             \
          (__attribute__((address_space(3))) void*)(smem + (boff) + i * 4096 + dwave), \
          16, 0, 0);                                                                   \
    _Pragma("unroll")                                                                  \
    for (int i = 0; i < 4; ++i)                                                        \
      __builtin_amdgcn_global_load_lds(                                                \
          (const __attribute__((address_space(1))) void*)(gB[i] + (koff)),             \
          (__attribute__((address_space(3))) void*)(smem + (boff) + ASZ + i * 4096 + dwave), \
          16, 0, 0);                                                                   \
  } while (0)

  STAGE(0, 0);
  __syncthreads();
  unsigned buf = 0;
  const int nsteps = K >> 6;
  for (int s = 0; s < nsteps; ++s) {
    if (s + 1 < nsteps) STAGE((s + 1) << 6, buf ^ HALF);  // prefetch next K-tile
    const unsigned short* sb = smem + buf;
#pragma unroll
    for (int ks = 0; ks < 2; ++ks) {
      short8 af[MI], bf[4];
#pragma unroll
      for (int mi = 0; mi < MI; ++mi) af[mi] = *(const short8*)&sb[offA[mi][ks]];
#pragma unroll
      for (int ni = 0; ni < 4; ++ni) bf[ni] = *(const short8*)&sb[offB[ni][ks]];
#pragma unroll
      for (int mi = 0; mi < MI; ++mi)
#pragma unroll
        for (int ni = 0; ni < 4; ++ni)
          acc[mi][ni] = __builtin_amdgcn_mfma_f32_16x16x32_bf16(af[mi], bf[ni],
                                                                acc[mi][ni], 0, 0, 0);
    }
    __syncthreads();  // drains vmcnt: next tile landed; all reads of buf done
    buf ^= HALF;
  }
#undef STAGE

  if (EPI == 0) {
    // cross -> dist -> weight -> swizzled LDS bounce; per-row partial sums.
    float ps[4], rt[4];
#pragma unroll
    for (int ni = 0; ni < 4; ++ni) {
      const int col = bn * 256 + wn * 64 + ni * 16 + lr;
      ps[ni] = psq[col];
      rt[ni] = rtemp[col];
    }
    float* slice = part + (size_t)(bn * 4 + wn) * Mtot;
#pragma unroll
    for (int mi = 0; mi < MI; ++mi) {
#pragma unroll
      for (int j = 0; j < 4; ++j) {
        const int lrow = wm * (MI * 16) + mi * 16 + lg * 4 + j;
        const int grow = row0 + bm * BM + lrow;
        const float xq = xsq[grow];
        float rsv = 0.f;
#pragma unroll
        for (int ni = 0; ni < 4; ++ni) {
          const int lcol = wn * 64 + ni * 16 + lr;
          float d2 = xq + ps[ni] - 2.0f * acc[mi][ni][j];
          float dist = __builtin_amdgcn_sqrtf(fmaxf(d2, 0.0f));
          float w = __expf(-dist * rt[ni]);
          smem[lrow * 256 + (((lcol >> 3) ^ (lrow & 7)) << 3) + (lcol & 7)] = f2bf(w);
          rsv += w;
        }
        rsv += __shfl_xor(rsv, 1);
        rsv += __shfl_xor(rsv, 2);
        rsv += __shfl_xor(rsv, 4);
        rsv += __shfl_xor(rsv, 8);
        if (lr == 0) slice[grow] = rsv;
      }
    }
    __syncthreads();
    // coalesced nontemporal copy-out: BM*32 16B-chunks
#pragma unroll
    for (int i = 0; i < BM / 16; ++i) {
      const int id = i * 512 + t;
      const int r = id >> 5, h = id & 31;
      short8 v = *(const short8*)&smem[r * 256 + ((h ^ (r & 7)) << 3)];
      __builtin_nontemporal_store(v,
          (short8*)&Wout[(size_t)(bm * BM + r) * ldOut + bn * 256 + h * 8]);
    }
  } else {
    // scale by 1/denom at copy-out; bounce fp32 tile for full-line stores
    float* smemf = (float*)smem;
#pragma unroll
    for (int mi = 0; mi < MI; ++mi)
#pragma unroll
      for (int j = 0; j < 4; ++j) {
        const int lrow = wm * (MI * 16) + mi * 16 + lg * 4 + j;
#pragma unroll
        for (int ni = 0; ni < 4; ++ni) {
          const int lcol = wn * 64 + ni * 16 + lr;
          smemf[lrow * 256 + (((lcol >> 2) ^ (lrow & 7)) << 2) + (lcol & 3)] =
              acc[mi][ni][j];
        }
      }
    __syncthreads();
#pragma unroll
    for (int i = 0; i < BM / 8; ++i) {  // BM*64 16B-chunks / 512
      const int id = i * 512 + t;
      const int r = id >> 6, h = id & 63;  // r uniform per wave
      const int grow = row0 + bm * BM + r;
      const float rd = 1.0f / (denin[grow] + 1e-8f);
      f32x4 v = *(const f32x4*)&smemf[r * 256 + ((h ^ (r & 7)) << 2)];
      v *= rd;
      __builtin_nontemporal_store(v,
          (f32x4*)&outp[(size_t)grow * ldOut + bn * 256 + h * 4]);
    }
  }
}

// denom[m] = sum_s part[s][m]
__global__ void reduce_denom(const float* __restrict__ part, float* __restrict__ denom,
                             int Mtot, int row0, int S) {
  const int m = row0 + blockIdx.x * 128 + threadIdx.x;
  float s = 0.f;
  for (int i = 0; i < S; ++i) s += part[(size_t)i * Mtot + m];
  denom[m] = s;
}

// One block per row: cast fp32 row -> bf16, compute sum of squares.
__global__ void prep_rows(const float* __restrict__ in, unsigned short* __restrict__ outb,
                          float* __restrict__ sq, int D) {
  const int row = blockIdx.x;
  const int t = threadIdx.x;
  const float4 v = ((const float4*)(in + (size_t)row * D))[t];
  u16x4 o = {f2bf(v.x), f2bf(v.y), f2bf(v.z), f2bf(v.w)};
  *(u16x4*)(outb + (size_t)row * D + t * 4) = o;
  float s = v.x * v.x + v.y * v.y + v.z * v.z + v.w * v.w;
  for (int off = 32; off; off >>= 1) s += __shfl_xor(s, off);
  __shared__ float ws[16];
  if ((t & 63) == 0) ws[t >> 6] = s;
  __syncthreads();
  if (t == 0) {
    float tot = 0.f;
    const int nw = blockDim.x >> 6;
    for (int i = 0; i < nw; ++i) tot += ws[i];
    sq[row] = tot;
  }
}

__global__ void prep_scale(const float* __restrict__ tmp, const float* __restrict__ sc,
                           float* __restrict__ rtemp, int N) {
  const int i = blockIdx.x * blockDim.x + threadIdx.x;
  if (i < N) rtemp[i] = 1.0f / ((fabsf(tmp[i]) + 0.1f) * sc[i]);
}

// Transpose values [N][D] fp32 -> vT [D][N] bf16
__global__ void prep_vT(const float* __restrict__ vals, unsigned short* __restrict__ vT,
                        int N, int D) {
  __shared__ float tile[32][33];
  const int nt = blockIdx.x, dt = blockIdx.y;
  const int tx = threadIdx.x, ty = threadIdx.y;  // (32, 8)
#pragma unroll
  for (int i = 0; i < 4; ++i) {
    int r = nt * 32 + ty + i * 8;
    tile[ty + i * 8][tx] = vals[(size_t)r * D + dt * 32 + tx];
  }
  __syncthreads();
#pragma unroll
  for (int i = 0; i < 4; ++i) {
    int d = dt * 32 + ty + i * 8;
    vT[(size_t)d * N + nt * 32 + tx] = f2bf(tile[tx][ty + i * 8]);
  }
}

extern "C" void kernel_launch(void* const* d_in, const int* in_sizes, int n_in,
                              void* d_out, int out_size, void* d_ws, size_t ws_size,
                              hipStream_t stream) {
  const float* x = (const float*)d_in[0];
  const float* pos = (const float*)d_in[1];
  const float* vals = (const float*)d_in[2];
  const float* temp = (const float*)d_in[3];
  const float* nsc = (const float*)d_in[4];
  float* out = (float*)d_out;

  const int N = in_sizes[3];          // 4096
  const int D = in_sizes[1] / N;      // 512
  const int M = in_sizes[0] / D;      // 16384
  const int S = 4 * (N / 256);        // partial slices (64)

  char* ws = (char*)d_ws;
  size_t off = 0;
  auto alloc = [&](size_t bytes) {
    void* p = ws + off;
    off = (off + bytes + 255) & ~(size_t)255;
    return p;
  };
  unsigned short* xb = (unsigned short*)alloc((size_t)M * D * 2);
  unsigned short* pb = (unsigned short*)alloc((size_t)N * D * 2);
  unsigned short* vT = (unsigned short*)alloc((size_t)D * N * 2);
  float* xsq = (float*)alloc((size_t)M * 4);
  float* psq = (float*)alloc((size_t)N * 4);
  float* rtemp = (float*)alloc((size_t)N * 4);
  float* denom = (float*)alloc((size_t)M * 4);
  float* part = (float*)alloc((size_t)S * M * 4);

  size_t avail = ws_size > off ? ws_size - off : 0;
  long long mc_ll = (long long)(avail / ((size_t)N * 2));
  int Mc = (int)((mc_ll / 256) * 256);
  if (Mc > M) Mc = M;
  if (Mc < 256) Mc = 256;  // minimal fallback
  unsigned short* W = (unsigned short*)alloc((size_t)Mc * N * 2);

  prep_rows<<<M, D / 4, 0, stream>>>(x, xb, xsq, D);
  prep_rows<<<N, D / 4, 0, stream>>>(pos, pb, psq, D);
  prep_scale<<<(N + 255) / 256, 256, 0, stream>>>(temp, nsc, rtemp, N);
  dim3 tg(N / 32, D / 32);
  prep_vT<<<tg, dim3(32, 8), 0, stream>>>(vals, vT, N, D);

  for (int row0 = 0; row0 < M; row0 += Mc) {
    const int mc = (M - row0) < Mc ? (M - row0) : Mc;
    const int g1 = (mc / 256) * (N / 256);
    rbf_gemm<0, 8><<<g1, 512, 0, stream>>>(xb + (size_t)row0 * D, pb, N, D,
                                           xsq, psq, rtemp, W, part, M,
                                           nullptr, nullptr, row0, N);
    reduce_denom<<<mc / 128, 128, 0, stream>>>(part, denom, M, row0, S);
    const int g2 = (mc / 128) * (D / 256);
    rbf_gemm<1, 4><<<g2, 512, 0, stream>>>(W, vT, D, N,
                                           nullptr, nullptr, nullptr, nullptr,
                                           part, M, denom, out, row0, D);
  }
}

// Round 8
// 218.477 us; speedup vs baseline: 1.0669x; 1.0669x over previous
//
#include <hip/hip_runtime.h>
#include <hip/hip_bf16.h>

typedef __attribute__((ext_vector_type(8))) short short8;
typedef __attribute__((ext_vector_type(4))) float f32x4;
typedef __attribute__((ext_vector_type(4))) unsigned short u16x4;

__device__ __forceinline__ unsigned short f2bf(float f) {
  union { float f; unsigned u; } v; v.f = f;
  unsigned r = v.u + 0x7fffu + ((v.u >> 16) & 1u);
  return (unsigned short)(r >> 16);
}

// C = A * Bt^T. 512 threads = 8 waves (2M x 4N), wave-tile (MI*16) x 64,
// BK=64, double-buffered with COUNTED vmcnt (T4): stage(s+1) issued before
// compute(s); s_waitcnt vmcnt(LOADS) waits only stage(s); prefetch stays in
// flight across the barriers and drains under the MFMA phase.
// EPI=0: MI=8 -> 256x256 tile; epilogue: W bf16 via swizzled LDS bounce +
//        row-sum partials into part[(bn*4+wn)][row] (unique writer).
// EPI=1: MI=4 -> 128x256 tile; epilogue: out fp32 * 1/(denin+1e-8) via LDS
//        bounce -> coalesced nontemporal stores.
// LDS staging swizzle: row r (8x16B chunks) holds global chunk c^(r&7) at
// slot c; applied global-side (linear gload_lds dest) + reader-side.
template <int EPI, int MI>
__global__ __launch_bounds__(512, 2) void rbf_gemm(
    const unsigned short* __restrict__ A, const unsigned short* __restrict__ Bt,
    int Ncols, int K,
    const float* __restrict__ xsq, const float* __restrict__ psq,
    const float* __restrict__ rtemp, unsigned short* __restrict__ Wout,
    float* __restrict__ part, int Mtot, const float* __restrict__ denin,
    float* __restrict__ outp, int row0, int ldOut) {
  constexpr int BM = MI * 32;          // 256 or 128
  constexpr int AITERS = BM / 64;      // 4 or 2
  constexpr int LOADS = AITERS + 4;    // gload_lds per thread per stage
  constexpr int ASZ = BM * 64;         // A elems per K-tile
  constexpr int HALF = ASZ + 16384;    // + B (256 rows x 64)
  __shared__ __align__(16) unsigned short smem[65536];  // 128 KB

  const int t = threadIdx.x;
  const int lane = t & 63, wid = t >> 6;
  const int wm = wid >> 2, wn = wid & 3;   // 2M x 4N waves
  const int lr = lane & 15, lg = lane >> 4;

  const int nb = Ncols >> 8;
  const int nwg = gridDim.x;
  int swz = blockIdx.x;
  if ((nwg & 7) == 0) {  // bijective XCD swizzle
    int cpx = nwg >> 3;
    swz = (swz & 7) * cpx + (swz >> 3);
  }
  const int bm = swz / nb, bn = swz - bm * nb;

  const unsigned short* Ab = A + (size_t)bm * BM * K;
  const unsigned short* Bb = Bt + (size_t)bn * 256 * K;

  // staging source pointers (swizzled chunk), advance by koff per step
  const unsigned short* gA[AITERS];
  const unsigned short* gB[4];
#pragma unroll
  for (int i = 0; i < AITERS; ++i) {
    const int idx = i * 512 + t;
    const int r = idx >> 3, c = idx & 7;
    gA[i] = Ab + (size_t)r * K + ((c ^ (r & 7)) << 3);
  }
#pragma unroll
  for (int i = 0; i < 4; ++i) {
    const int idx = i * 512 + t;
    const int r = idx >> 3, c = idx & 7;
    gB[i] = Bb + (size_t)r * K + ((c ^ (r & 7)) << 3);
  }
  const int dwave = wid << 9;  // wave-uniform LDS elem base within a 512-slot group

  // fragment LDS element offsets (reader applies same swizzle)
  int offA[MI][2], offB[4][2];
#pragma unroll
  for (int mi = 0; mi < MI; ++mi) {
    const int ar = wm * (MI * 16) + mi * 16 + lr;
#pragma unroll
    for (int ks = 0; ks < 2; ++ks)
      offA[mi][ks] = ar * 64 + ((((ks << 2) | lg) ^ (ar & 7)) << 3);
  }
#pragma unroll
  for (int ni = 0; ni < 4; ++ni) {
    const int br = wn * 64 + ni * 16 + lr;
#pragma unroll
    for (int ks = 0; ks < 2; ++ks)
      offB[ni][ks] = ASZ + br * 64 + ((((ks << 2) | lg) ^ (br & 7)) << 3);
  }

  f32x4 acc[MI][4];
#pragma unroll
  for (int i = 0; i < MI; ++i)
#pragma unroll
    for (int j = 0; j < 4; ++j) acc[i][j] = (f32x4){0.f, 0.f, 0.f, 0.f};

#define STAGE(koff, boff)                                                              \
  do {                                                                                 \
    _Pragma("unroll")                                                                  \
    for (int i = 0; i < AITERS; ++i)                                                   \
      __builtin_amdgcn_global_load_lds(                                                \
          (const __attribute__((address_space(1))) void*)(gA[i] + (koff)),             \
          (__attribute__((address_space(3))) void*)(smem + (boff) + i * 4096 + dwave), \
          16, 0, 0);                                                                   \
    _Pragma("unroll")                                                                  \
    for (int i = 0; i < 4; ++i)                                                        \
      __builtin_amdgcn_global_load_lds(                                                \
          (const __attribute__((address_space(1))) void*)(gB[i] + (koff)),             \
          (__attribute__((address_space(3))) void*)(smem + (boff) + ASZ + i * 4096 + dwave), \
          16, 0, 0);                                                                   \
  } while (0)

  STAGE(0, 0);  // prologue; completion enforced by first-iter vmcnt(LOADS)
  unsigned buf = 0;
  const int nsteps = K >> 6;
  for (int s = 0; s < nsteps; ++s) {
    if (s + 1 < nsteps) {
      STAGE((s + 1) << 6, buf ^ HALF);  // prefetch next K-tile (stays in flight)
      asm volatile("s_waitcnt vmcnt(%0)" :: "i"(LOADS) : "memory");  // stage(s) landed
    } else {
      asm volatile("s_waitcnt vmcnt(0)" ::: "memory");  // last tile: full wait
    }
    __builtin_amdgcn_s_barrier();       // all waves' stage(s) landed
    const unsigned short* sb = smem + buf;
#pragma unroll
    for (int ks = 0; ks < 2; ++ks) {
      short8 af[MI], bf[4];
#pragma unroll
      for (int mi = 0; mi < MI; ++mi) af[mi] = *(const short8*)&sb[offA[mi][ks]];
#pragma unroll
      for (int ni = 0; ni < 4; ++ni) bf[ni] = *(const short8*)&sb[offB[ni][ks]];
#pragma unroll
      for (int mi = 0; mi < MI; ++mi)
#pragma unroll
        for (int ni = 0; ni < 4; ++ni)
          acc[mi][ni] = __builtin_amdgcn_mfma_f32_16x16x32_bf16(af[mi], bf[ni],
                                                                acc[mi][ni], 0, 0, 0);
    }
    asm volatile("s_waitcnt lgkmcnt(0)" ::: "memory");  // ds_reads drained
    __builtin_amdgcn_s_barrier();       // safe to overwrite buf next iter
    buf ^= HALF;
  }
#undef STAGE

  if (EPI == 0) {
    // cross -> dist -> weight -> swizzled LDS bounce; per-row partial sums.
    float ps[4], rt[4];
#pragma unroll
    for (int ni = 0; ni < 4; ++ni) {
      const int col = bn * 256 + wn * 64 + ni * 16 + lr;
      ps[ni] = psq[col];
      rt[ni] = rtemp[col];
    }
    float* slice = part + (size_t)(bn * 4 + wn) * Mtot;
#pragma unroll
    for (int mi = 0; mi < MI; ++mi) {
#pragma unroll
      for (int j = 0; j < 4; ++j) {
        const int lrow = wm * (MI * 16) + mi * 16 + lg * 4 + j;
        const int grow = row0 + bm * BM + lrow;
        const float xq = xsq[grow];
        float rsv = 0.f;
#pragma unroll
        for (int ni = 0; ni < 4; ++ni) {
          const int lcol = wn * 64 + ni * 16 + lr;
          float d2 = xq + ps[ni] - 2.0f * acc[mi][ni][j];
          float dist = __builtin_amdgcn_sqrtf(fmaxf(d2, 0.0f));
          float w = __expf(-dist * rt[ni]);
          smem[lrow * 256 + (((lcol >> 3) ^ (lrow & 7)) << 3) + (lcol & 7)] = f2bf(w);
          rsv += w;
        }
        rsv += __shfl_xor(rsv, 1);
        rsv += __shfl_xor(rsv, 2);
        rsv += __shfl_xor(rsv, 4);
        rsv += __shfl_xor(rsv, 8);
        if (lr == 0) slice[grow] = rsv;
      }
    }
    __syncthreads();
    // coalesced nontemporal copy-out: BM*32 16B-chunks
#pragma unroll
    for (int i = 0; i < BM / 16; ++i) {
      const int id = i * 512 + t;
      const int r = id >> 5, h = id & 31;
      short8 v = *(const short8*)&smem[r * 256 + ((h ^ (r & 7)) << 3)];
      __builtin_nontemporal_store(v,
          (short8*)&Wout[(size_t)(bm * BM + r) * ldOut + bn * 256 + h * 8]);
    }
  } else {
    // scale by 1/denom at copy-out; bounce fp32 tile for full-line stores
    float* smemf = (float*)smem;
#pragma unroll
    for (int mi = 0; mi < MI; ++mi)
#pragma unroll
      for (int j = 0; j < 4; ++j) {
        const int lrow = wm * (MI * 16) + mi * 16 + lg * 4 + j;
#pragma unroll
        for (int ni = 0; ni < 4; ++ni) {
          const int lcol = wn * 64 + ni * 16 + lr;
          smemf[lrow * 256 + (((lcol >> 2) ^ (lrow & 7)) << 2) + (lcol & 3)] =
              acc[mi][ni][j];
        }
      }
    __syncthreads();
#pragma unroll
    for (int i = 0; i < BM / 8; ++i) {  // BM*64 16B-chunks / 512
      const int id = i * 512 + t;
      const int r = id >> 6, h = id & 63;  // r uniform per wave
      const int grow = row0 + bm * BM + r;
      const float rd = 1.0f / (denin[grow] + 1e-8f);
      f32x4 v = *(const f32x4*)&smemf[r * 256 + ((h ^ (r & 7)) << 2)];
      v *= rd;
      __builtin_nontemporal_store(v,
          (f32x4*)&outp[(size_t)grow * ldOut + bn * 256 + h * 4]);
    }
  }
}

// denom[m] = sum_s part[s][m]
__global__ void reduce_denom(const float* __restrict__ part, float* __restrict__ denom,
                             int Mtot, int row0, int S) {
  const int m = row0 + blockIdx.x * 128 + threadIdx.x;
  float s = 0.f;
  for (int i = 0; i < S; ++i) s += part[(size_t)i * Mtot + m];
  denom[m] = s;
}

// One block per row: cast fp32 row -> bf16, compute sum of squares.
__global__ void prep_rows(const float* __restrict__ in, unsigned short* __restrict__ outb,
                          float* __restrict__ sq, int D) {
  const int row = blockIdx.x;
  const int t = threadIdx.x;
  const float4 v = ((const float4*)(in + (size_t)row * D))[t];
  u16x4 o = {f2bf(v.x), f2bf(v.y), f2bf(v.z), f2bf(v.w)};
  *(u16x4*)(outb + (size_t)row * D + t * 4) = o;
  float s = v.x * v.x + v.y * v.y + v.z * v.z + v.w * v.w;
  for (int off = 32; off; off >>= 1) s += __shfl_xor(s, off);
  __shared__ float ws[16];
  if ((t & 63) == 0) ws[t >> 6] = s;
  __syncthreads();
  if (t == 0) {
    float tot = 0.f;
    const int nw = blockDim.x >> 6;
    for (int i = 0; i < nw; ++i) tot += ws[i];
    sq[row] = tot;
  }
}

__global__ void prep_scale(const float* __restrict__ tmp, const float* __restrict__ sc,
                           float* __restrict__ rtemp, int N) {
  const int i = blockIdx.x * blockDim.x + threadIdx.x;
  if (i < N) rtemp[i] = 1.0f / ((fabsf(tmp[i]) + 0.1f) * sc[i]);
}

// Transpose values [N][D] fp32 -> vT [D][N] bf16
__global__ void prep_vT(const float* __restrict__ vals, unsigned short* __restrict__ vT,
                        int N, int D) {
  __shared__ float tile[32][33];
  const int nt = blockIdx.x, dt = blockIdx.y;
  const int tx = threadIdx.x, ty = threadIdx.y;  // (32, 8)
#pragma unroll
  for (int i = 0; i < 4; ++i) {
    int r = nt * 32 + ty + i * 8;
    tile[ty + i * 8][tx] = vals[(size_t)r * D + dt * 32 + tx];
  }
  __syncthreads();
#pragma unroll
  for (int i = 0; i < 4; ++i) {
    int d = dt * 32 + ty + i * 8;
    vT[(size_t)d * N + nt * 32 + tx] = f2bf(tile[tx][ty + i * 8]);
  }
}

extern "C" void kernel_launch(void* const* d_in, const int* in_sizes, int n_in,
                              void* d_out, int out_size, void* d_ws, size_t ws_size,
                              hipStream_t stream) {
  const float* x = (const float*)d_in[0];
  const float* pos = (const float*)d_in[1];
  const float* vals = (const float*)d_in[2];
  const float* temp = (const float*)d_in[3];
  const float* nsc = (const float*)d_in[4];
  float* out = (float*)d_out;

  const int N = in_sizes[3];          // 4096
  const int D = in_sizes[1] / N;      // 512
  const int M = in_sizes[0] / D;      // 16384
  const int S = 4 * (N / 256);        // partial slices (64)

  char* ws = (char*)d_ws;
  size_t off = 0;
  auto alloc = [&](size_t bytes) {
    void* p = ws + off;
    off = (off + bytes + 255) & ~(size_t)255;
    return p;
  };
  unsigned short* xb = (unsigned short*)alloc((size_t)M * D * 2);
  unsigned short* pb = (unsigned short*)alloc((size_t)N * D * 2);
  unsigned short* vT = (unsigned short*)alloc((size_t)D * N * 2);
  float* xsq = (float*)alloc((size_t)M * 4);
  float* psq = (float*)alloc((size_t)N * 4);
  float* rtemp = (float*)alloc((size_t)N * 4);
  float* denom = (float*)alloc((size_t)M * 4);
  float* part = (float*)alloc((size_t)S * M * 4);

  size_t avail = ws_size > off ? ws_size - off : 0;
  long long mc_ll = (long long)(avail / ((size_t)N * 2));
  int Mc = (int)((mc_ll / 256) * 256);
  if (Mc > M) Mc = M;
  if (Mc < 256) Mc = 256;  // minimal fallback
  unsigned short* W = (unsigned short*)alloc((size_t)Mc * N * 2);

  prep_rows<<<M, D / 4, 0, stream>>>(x, xb, xsq, D);
  prep_rows<<<N, D / 4, 0, stream>>>(pos, pb, psq, D);
  prep_scale<<<(N + 255) / 256, 256, 0, stream>>>(temp, nsc, rtemp, N);
  dim3 tg(N / 32, D / 32);
  prep_vT<<<tg, dim3(32, 8), 0, stream>>>(vals, vT, N, D);

  for (int row0 = 0; row0 < M; row0 += Mc) {
    const int mc = (M - row0) < Mc ? (M - row0) : Mc;
    const int g1 = (mc / 256) * (N / 256);
    rbf_gemm<0, 8><<<g1, 512, 0, stream>>>(xb + (size_t)row0 * D, pb, N, D,
                                           xsq, psq, rtemp, W, part, M,
                                           nullptr, nullptr, row0, N);
    reduce_denom<<<mc / 128, 128, 0, stream>>>(part, denom, M, row0, S);
    const int g2 = (mc / 128) * (D / 256);
    rbf_gemm<1, 4><<<g2, 512, 0, stream>>>(W, vT, D, N,
                                           nullptr, nullptr, nullptr, nullptr,
                                           part, M, denom, out, row0, D);
  }
}

// Round 9
// 214.105 us; speedup vs baseline: 1.0887x; 1.0204x over previous
//
#include <hip/hip_runtime.h>
#include <hip/hip_bf16.h>

typedef __attribute__((ext_vector_type(8))) short short8;
typedef __attribute__((ext_vector_type(4))) float f32x4;
typedef __attribute__((ext_vector_type(4))) unsigned short u16x4;

__device__ __forceinline__ unsigned short f2bf(float f) {
  union { float f; unsigned u; } v; v.f = f;
  unsigned r = v.u + 0x7fffu + ((v.u >> 16) & 1u);
  return (unsigned short)(r >> 16);
}

// C = A * Bt^T. 512 threads = 8 waves (WM x WN), wave-tile (MI*16) x 64,
// BK=64, double-buffered, counted vmcnt: stage(s+1) issued before compute(s),
// s_waitcnt vmcnt(LOADS) waits only stage(s); prefetch drains under MFMA.
// Pass A: EPI=0, WM=4,WN=2,MI=2 -> 128x128 tile, LDS 64 KB (2 blocks/CU).
//   Epilogue: w = exp2(-dist * rt2) (rt2 has log2e folded), W bf16 via
//   swizzled LDS bounce -> NT stores; row-sum partials (unique writer).
// Pass B: EPI=1, WM=2,WN=4,MI=4 -> 128x256 tile, LDS 128 KB (1 block/CU).
//   Epilogue: out fp32 * 1/(denin+1e-8) via LDS bounce -> NT stores.
// LDS staging swizzle: row r (8x16B chunks) holds global chunk c^(r&7) at
// slot c; applied global-side (linear gload_lds dest) + reader-side.
template <int EPI, int WM, int WN, int MI>
__global__ __launch_bounds__(512, 4) void rbf_gemm(
    const unsigned short* __restrict__ A, const unsigned short* __restrict__ Bt,
    int Ncols, int K,
    const float* __restrict__ xsq, const float* __restrict__ psq,
    const float* __restrict__ rtemp, unsigned short* __restrict__ Wout,
    float* __restrict__ part, int Mtot, const float* __restrict__ denin,
    float* __restrict__ outp, int row0, int ldOut) {
  constexpr int BM = WM * MI * 16;       // 128
  constexpr int BN = WN * 64;            // 128 or 256
  constexpr int AITERS = BM / 64;        // staging iters for A (2)
  constexpr int BITERS = BN / 64;        // staging iters for B (2 or 4)
  constexpr int LOADS = AITERS + BITERS; // gload_lds per thread per stage
  constexpr int ASZ = BM * 64;           // A elems per K-tile
  constexpr int HALF = ASZ + BN * 64;    // elems per dbuf half
  constexpr int BOUNCE = EPI == 1 ? BM * BN * 2 : BM * BN;  // shorts
  constexpr int SELEMS = 2 * HALF > BOUNCE ? 2 * HALF : BOUNCE;
  __shared__ __align__(16) unsigned short smem[SELEMS];

  const int t = threadIdx.x;
  const int lane = t & 63, wid = t >> 6;
  const int wm = wid / WN, wn = wid % WN;
  const int lr = lane & 15, lg = lane >> 4;

  const int nb = Ncols / BN;
  const int nwg = gridDim.x;
  int swz = blockIdx.x;
  if ((nwg & 7) == 0) {  // bijective XCD swizzle
    int cpx = nwg >> 3;
    swz = (swz & 7) * cpx + (swz >> 3);
  }
  const int bm = swz / nb, bn = swz - bm * nb;

  const unsigned short* Ab = A + (size_t)bm * BM * K;
  const unsigned short* Bb = Bt + (size_t)bn * BN * K;

  // staging source pointers (swizzled chunk), advance by koff per step
  const unsigned short* gA[AITERS];
  const unsigned short* gB[BITERS];
#pragma unroll
  for (int i = 0; i < AITERS; ++i) {
    const int idx = i * 512 + t;
    const int r = idx >> 3, c = idx & 7;
    gA[i] = Ab + (size_t)r * K + ((c ^ (r & 7)) << 3);
  }
#pragma unroll
  for (int i = 0; i < BITERS; ++i) {
    const int idx = i * 512 + t;
    const int r = idx >> 3, c = idx & 7;
    gB[i] = Bb + (size_t)r * K + ((c ^ (r & 7)) << 3);
  }
  const int dwave = wid << 9;  // wave-uniform LDS elem base (64 slots * 8)

  // fragment LDS element offsets (reader applies same swizzle)
  int offA[MI][2], offB[4][2];
#pragma unroll
  for (int mi = 0; mi < MI; ++mi) {
    const int ar = wm * (MI * 16) + mi * 16 + lr;
#pragma unroll
    for (int ks = 0; ks < 2; ++ks)
      offA[mi][ks] = ar * 64 + ((((ks << 2) | lg) ^ (ar & 7)) << 3);
  }
#pragma unroll
  for (int ni = 0; ni < 4; ++ni) {
    const int br = wn * 64 + ni * 16 + lr;
#pragma unroll
    for (int ks = 0; ks < 2; ++ks)
      offB[ni][ks] = ASZ + br * 64 + ((((ks << 2) | lg) ^ (br & 7)) << 3);
  }

  f32x4 acc[MI][4];
#pragma unroll
  for (int i = 0; i < MI; ++i)
#pragma unroll
    for (int j = 0; j < 4; ++j) acc[i][j] = (f32x4){0.f, 0.f, 0.f, 0.f};

#define STAGE(koff, boff)                                                              \
  do {                                                                                 \
    _Pragma("unroll")                                                                  \
    for (int i = 0; i < AITERS; ++i)                                                   \
      __builtin_amdgcn_global_load_lds(                                                \
          (const __attribute__((address_space(1))) void*)(gA[i] + (koff)),             \
          (__attribute__((address_space(3))) void*)(smem + (boff) + i * 4096 + dwave), \
          16, 0, 0);                                                                   \
    _Pragma("unroll")                                                                  \
    for (int i = 0; i < BITERS; ++i)                                                   \
      __builtin_amdgcn_global_load_lds(                                                \
          (const __attribute__((address_space(1))) void*)(gB[i] + (koff)),             \
          (__attribute__((address_space(3))) void*)(smem + (boff) + ASZ + i * 4096 + dwave), \
          16, 0, 0);                                                                   \
  } while (0)

  STAGE(0, 0);  // prologue; completion enforced by first-iter vmcnt
  unsigned buf = 0;
  const int nsteps = K >> 6;
  for (int s = 0; s < nsteps; ++s) {
    if (s + 1 < nsteps) {
      STAGE((s + 1) << 6, buf ^ HALF);  // prefetch next K-tile (stays in flight)
      asm volatile("s_waitcnt vmcnt(%0)" :: "i"(LOADS) : "memory");  // stage(s) landed
    } else {
      asm volatile("s_waitcnt vmcnt(0)" ::: "memory");  // last tile: full wait
    }
    __builtin_amdgcn_s_barrier();       // all waves' stage(s) landed
    const unsigned short* sb = smem + buf;
    __builtin_amdgcn_s_setprio(1);
#pragma unroll
    for (int ks = 0; ks < 2; ++ks) {
      short8 af[MI], bf[4];
#pragma unroll
      for (int mi = 0; mi < MI; ++mi) af[mi] = *(const short8*)&sb[offA[mi][ks]];
#pragma unroll
      for (int ni = 0; ni < 4; ++ni) bf[ni] = *(const short8*)&sb[offB[ni][ks]];
#pragma unroll
      for (int mi = 0; mi < MI; ++mi)
#pragma unroll
        for (int ni = 0; ni < 4; ++ni)
          acc[mi][ni] = __builtin_amdgcn_mfma_f32_16x16x32_bf16(af[mi], bf[ni],
                                                                acc[mi][ni], 0, 0, 0);
    }
    __builtin_amdgcn_s_setprio(0);
    asm volatile("s_waitcnt lgkmcnt(0)" ::: "memory");  // ds_reads drained
    __builtin_amdgcn_s_barrier();       // safe to overwrite buf next iter
    buf ^= HALF;
  }
#undef STAGE

  if (EPI == 0) {
    // cross -> dist -> weight -> swizzled LDS bounce; per-row partial sums.
    float ps[4], rt[4];
#pragma unroll
    for (int ni = 0; ni < 4; ++ni) {
      const int col = bn * BN + wn * 64 + ni * 16 + lr;
      ps[ni] = psq[col];
      rt[ni] = rtemp[col];  // log2e / effective_temp
    }
    float* slice = part + (size_t)(bn * WN + wn) * Mtot;
#pragma unroll
    for (int mi = 0; mi < MI; ++mi) {
#pragma unroll
      for (int j = 0; j < 4; ++j) {
        const int lrow = wm * (MI * 16) + mi * 16 + lg * 4 + j;
        const int grow = row0 + bm * BM + lrow;
        const float xq = xsq[grow];
        float rsv = 0.f;
#pragma unroll
        for (int ni = 0; ni < 4; ++ni) {
          const int lcol = wn * 64 + ni * 16 + lr;
          float d2 = xq + ps[ni] - 2.0f * acc[mi][ni][j];
          float dist = __builtin_amdgcn_sqrtf(fmaxf(d2, 0.0f));
          float w = __builtin_amdgcn_exp2f(-dist * rt[ni]);
          smem[lrow * BN + (((lcol >> 3) ^ (lrow & 7)) << 3) + (lcol & 7)] = f2bf(w);
          rsv += w;
        }
        rsv += __shfl_xor(rsv, 1);
        rsv += __shfl_xor(rsv, 2);
        rsv += __shfl_xor(rsv, 4);
        rsv += __shfl_xor(rsv, 8);
        if (lr == 0) slice[grow] = rsv;
      }
    }
    __syncthreads();
    // coalesced nontemporal copy-out: BM*BN/8 16B-chunks
    constexpr int HB = BN / 8;
#pragma unroll
    for (int i = 0; i < BM * BN / 8 / 512; ++i) {
      const int id = i * 512 + t;
      const int r = id / HB, h = id % HB;
      short8 v = *(const short8*)&smem[r * BN + ((h ^ (r & 7)) << 3)];
      __builtin_nontemporal_store(v,
          (short8*)&Wout[(size_t)(bm * BM + r) * ldOut + bn * BN + h * 8]);
    }
  } else {
    // scale by 1/denom at copy-out; bounce fp32 tile for full-line stores
    float* smemf = (float*)smem;
#pragma unroll
    for (int mi = 0; mi < MI; ++mi)
#pragma unroll
      for (int j = 0; j < 4; ++j) {
        const int lrow = wm * (MI * 16) + mi * 16 + lg * 4 + j;
#pragma unroll
        for (int ni = 0; ni < 4; ++ni) {
          const int lcol = wn * 64 + ni * 16 + lr;
          smemf[lrow * BN + (((lcol >> 2) ^ (lrow & 7)) << 2) + (lcol & 3)] =
              acc[mi][ni][j];
        }
      }
    __syncthreads();
    constexpr int HB4 = BN / 4;
#pragma unroll
    for (int i = 0; i < BM * BN / 4 / 512; ++i) {
      const int id = i * 512 + t;
      const int r = id / HB4, h = id % HB4;
      const int grow = row0 + bm * BM + r;
      const float rd = 1.0f / (denin[grow] + 1e-8f);
      f32x4 v = *(const f32x4*)&smemf[r * BN + ((h ^ (r & 7)) << 2)];
      v *= rd;
      __builtin_nontemporal_store(v,
          (f32x4*)&outp[(size_t)grow * ldOut + bn * BN + h * 4]);
    }
  }
}

// denom[m] = sum_s part[s][m]
__global__ void reduce_denom(const float* __restrict__ part, float* __restrict__ denom,
                             int Mtot, int row0, int S) {
  const int m = row0 + blockIdx.x * 128 + threadIdx.x;
  float s = 0.f;
  for (int i = 0; i < S; ++i) s += part[(size_t)i * Mtot + m];
  denom[m] = s;
}

// One block per row: cast fp32 row -> bf16, compute sum of squares.
__global__ void prep_rows(const float* __restrict__ in, unsigned short* __restrict__ outb,
                          float* __restrict__ sq, int D) {
  const int row = blockIdx.x;
  const int t = threadIdx.x;
  const float4 v = ((const float4*)(in + (size_t)row * D))[t];
  u16x4 o = {f2bf(v.x), f2bf(v.y), f2bf(v.z), f2bf(v.w)};
  *(u16x4*)(outb + (size_t)row * D + t * 4) = o;
  float s = v.x * v.x + v.y * v.y + v.z * v.z + v.w * v.w;
  for (int off = 32; off; off >>= 1) s += __shfl_xor(s, off);
  __shared__ float ws[16];
  if ((t & 63) == 0) ws[t >> 6] = s;
  __syncthreads();
  if (t == 0) {
    float tot = 0.f;
    const int nw = blockDim.x >> 6;
    for (int i = 0; i < nw; ++i) tot += ws[i];
    sq[row] = tot;
  }
}

// rtemp = log2(e) / ((|T|+0.1)*scale): folds the exp->exp2 conversion.
__global__ void prep_scale(const float* __restrict__ tmp, const float* __restrict__ sc,
                           float* __restrict__ rtemp, int N) {
  const int i = blockIdx.x * blockDim.x + threadIdx.x;
  if (i < N) rtemp[i] = 1.4426950408889634f / ((fabsf(tmp[i]) + 0.1f) * sc[i]);
}

// Transpose values [N][D] fp32 -> vT [D][N] bf16
__global__ void prep_vT(const float* __restrict__ vals, unsigned short* __restrict__ vT,
                        int N, int D) {
  __shared__ float tile[32][33];
  const int nt = blockIdx.x, dt = blockIdx.y;
  const int tx = threadIdx.x, ty = threadIdx.y;  // (32, 8)
#pragma unroll
  for (int i = 0; i < 4; ++i) {
    int r = nt * 32 + ty + i * 8;
    tile[ty + i * 8][tx] = vals[(size_t)r * D + dt * 32 + tx];
  }
  __syncthreads();
#pragma unroll
  for (int i = 0; i < 4; ++i) {
    int d = dt * 32 + ty + i * 8;
    vT[(size_t)d * N + nt * 32 + tx] = f2bf(tile[tx][ty + i * 8]);
  }
}

extern "C" void kernel_launch(void* const* d_in, const int* in_sizes, int n_in,
                              void* d_out, int out_size, void* d_ws, size_t ws_size,
                              hipStream_t stream) {
  const float* x = (const float*)d_in[0];
  const float* pos = (const float*)d_in[1];
  const float* vals = (const float*)d_in[2];
  const float* temp = (const float*)d_in[3];
  const float* nsc = (const float*)d_in[4];
  float* out = (float*)d_out;

  const int N = in_sizes[3];          // 4096
  const int D = in_sizes[1] / N;      // 512
  const int M = in_sizes[0] / D;      // 16384
  const int S = 2 * (N / 128);        // partial slices (64): BN=128, WN=2

  char* ws = (char*)d_ws;
  size_t off = 0;
  auto alloc = [&](size_t bytes) {
    void* p = ws + off;
    off = (off + bytes + 255) & ~(size_t)255;
    return p;
  };
  unsigned short* xb = (unsigned short*)alloc((size_t)M * D * 2);
  unsigned short* pb = (unsigned short*)alloc((size_t)N * D * 2);
  unsigned short* vT = (unsigned short*)alloc((size_t)D * N * 2);
  float* xsq = (float*)alloc((size_t)M * 4);
  float* psq = (float*)alloc((size_t)N * 4);
  float* rtemp = (float*)alloc((size_t)N * 4);
  float* denom = (float*)alloc((size_t)M * 4);
  float* part = (float*)alloc((size_t)S * M * 4);

  size_t avail = ws_size > off ? ws_size - off : 0;
  long long mc_ll = (long long)(avail / ((size_t)N * 2));
  int Mc = (int)((mc_ll / 128) * 128);
  if (Mc > M) Mc = M;
  if (Mc < 128) Mc = 128;  // minimal fallback
  unsigned short* W = (unsigned short*)alloc((size_t)Mc * N * 2);

  prep_rows<<<M, D / 4, 0, stream>>>(x, xb, xsq, D);
  prep_rows<<<N, D / 4, 0, stream>>>(pos, pb, psq, D);
  prep_scale<<<(N + 255) / 256, 256, 0, stream>>>(temp, nsc, rtemp, N);
  dim3 tg(N / 32, D / 32);
  prep_vT<<<tg, dim3(32, 8), 0, stream>>>(vals, vT, N, D);

  for (int row0 = 0; row0 < M; row0 += Mc) {
    const int mc = (M - row0) < Mc ? (M - row0) : Mc;
    // pass A: 128x128 tile, 2 blocks/CU
    const int g1 = (mc / 128) * (N / 128);
    rbf_gemm<0, 4, 2, 2><<<g1, 512, 0, stream>>>(xb + (size_t)row0 * D, pb, N, D,
                                                 xsq, psq, rtemp, W, part, M,
                                                 nullptr, nullptr, row0, N);
    reduce_denom<<<mc / 128, 128, 0, stream>>>(part, denom, M, row0, S);
    // pass B: 128x256 tile
    const int g2 = (mc / 128) * (D / 256);
    rbf_gemm<1, 2, 4, 4><<<g2, 512, 0, stream>>>(W, vT, D, N,
                                                 nullptr, nullptr, nullptr, nullptr,
                                                 part, M, denom, out, row0, D);
  }
}